// Round 5
// baseline (4681.233 us; speedup 1.0000x reference)
//
#include <hip/hip_runtime.h>
#include <hip/hip_bf16.h>
#include <stdint.h>

// SimTransformer — all-fp32 I/O (established R1/R2), fp64 mask chain.
// q=xWqk^T (fp64), qn=q/max(||q||,1e-12) (fp64), cos=qn qn^T (fp64),
// mask cos>0.1 decided in fp64 (decision band ~1e-15 -> zero flips vs any
// fp64 reference). Values path (v bf16, attn@v fp32, LayerNorm fp32):
// continuous, error ~1e-2 << 0.108 threshold. Output fp32.
// ws need = 134.3 MB < 144.1 MB proven available (R2).
// R5: identical to R4 plus two semantics-neutral clamps in pv_ln (poison-proof
// against hypothetical partial-execution; no-ops on healthy runs).

typedef __bf16 bf16;
typedef float f4 __attribute__((ext_vector_type(4)));

#define CAP 768   // max neighbors/row ~370 expected (sigma_cos~0.0625, thr=1.6sigma)

// ---------------------------------------------------------------------------
// K1: Q[n,e] = sum_d X[n,d]*W[e,d] in fp64. 64x64 tile, 256 thr, k-panels 64.
// ---------------------------------------------------------------------------
__global__ __launch_bounds__(256) void proj_f64(const float* __restrict__ X,
                                                const float* __restrict__ W,
                                                double* __restrict__ Q) {
    __shared__ double As[64][66];
    __shared__ double Bs[64][66];
    const int t = threadIdx.x, tn = t >> 4, te = t & 15;
    const int n0 = blockIdx.x * 64, e0 = blockIdx.y * 64;
    double acc[4][4] = {};
    for (int p = 0; p < 8; ++p) {
        __syncthreads();
        for (int q = 0; q < 16; ++q) {
            int id = q * 256 + t, r = id >> 6, c = id & 63;
            As[r][c] = (double)X[(size_t)(n0 + r) * 512 + p * 64 + c];
            Bs[r][c] = (double)W[(size_t)(e0 + r) * 512 + p * 64 + c];
        }
        __syncthreads();
        for (int kk = 0; kk < 64; ++kk) {
            double av[4], bv[4];
            for (int i = 0; i < 4; ++i) av[i] = As[tn + 16 * i][kk];
            for (int j = 0; j < 4; ++j) bv[j] = Bs[te + 16 * j][kk];
            for (int i = 0; i < 4; ++i)
                for (int j = 0; j < 4; ++j) acc[i][j] += av[i] * bv[j];
        }
    }
    for (int i = 0; i < 4; ++i)
        for (int j = 0; j < 4; ++j)
            Q[(size_t)(n0 + tn + 16 * i) * 512 + e0 + te + 16 * j] = acc[i][j];
}

// ---------------------------------------------------------------------------
// K1b: V[n,e] = sum_d X[n,d]*Wv[e,d], fp32 accum, bf16 out (values path).
// ---------------------------------------------------------------------------
__global__ __launch_bounds__(256) void proj_v(const float* __restrict__ X,
                                              const float* __restrict__ W,
                                              bf16* __restrict__ C) {
    __shared__ float As[64][132];
    __shared__ float Bs[64][132];
    const int t = threadIdx.x, tn = t >> 4, te = t & 15;
    const int n0 = blockIdx.x * 64, e0 = blockIdx.y * 64;
    f4 acc[4][4] = {};
    for (int p = 0; p < 4; ++p) {
        __syncthreads();
        for (int q = 0; q < 8; ++q) {
            int id = q * 256 + t, r = id >> 5, c = (id & 31) * 4;
            *(f4*)&As[r][c] = *(const f4*)&X[(size_t)(n0 + r) * 512 + p * 128 + c];
            *(f4*)&Bs[r][c] = *(const f4*)&W[(size_t)(e0 + r) * 512 + p * 128 + c];
        }
        __syncthreads();
        for (int kk = 0; kk < 32; ++kk) {
            f4 av[4], bv[4];
            for (int i = 0; i < 4; ++i) av[i] = *(const f4*)&As[tn + 16 * i][kk * 4];
            for (int j = 0; j < 4; ++j) bv[j] = *(const f4*)&Bs[te + 16 * j][kk * 4];
            for (int i = 0; i < 4; ++i)
                for (int j = 0; j < 4; ++j) acc[i][j] += av[i] * bv[j];
        }
    }
    for (int i = 0; i < 4; ++i)
        for (int j = 0; j < 4; ++j) {
            f4 a = acc[i][j];
            C[(size_t)(n0 + tn + 16 * i) * 512 + e0 + te + 16 * j] =
                (bf16)((a.x + a.y) + (a.z + a.w));
        }
}

// ---------------------------------------------------------------------------
// K2: in-place fp64 normalize: q /= max(||q||, 1e-12). One thread per row.
// ---------------------------------------------------------------------------
__global__ __launch_bounds__(256) void norm_f64(double* __restrict__ Q) {
    const int row = blockIdx.x * 256 + threadIdx.x;
    double* q = Q + (size_t)row * 512;
    double s = 0.0;
    for (int e = 0; e < 512; ++e) s += q[e] * q[e];
    double nm = fmax(sqrt(s), 1e-12);
    for (int e = 0; e < 512; ++e) q[e] = q[e] / nm;
}

// ---------------------------------------------------------------------------
// K3: cos = qn qn^T in fp64; threshold cos > 0.1 (fp64); per-row ascending-m
// sparse lists (idx u16, val bf16). grid 256 = 4 b x 64 n-tiles, 256 thr.
// ---------------------------------------------------------------------------
__global__ __launch_bounds__(256) void qk_f64(const double* __restrict__ QN,
                                              uint32_t* __restrict__ counts,
                                              uint16_t* __restrict__ idxs,
                                              bf16* __restrict__ vals) {
    __shared__ double An[64][66];    // 33,792 B
    __shared__ double Bm[64][66];    // 33,792 B
    __shared__ double Uc[64][65];    // 33,280 B   (total ~101 KB, 1 wg/CU)
    const int t = threadIdx.x, tn = t >> 4, te = t & 15;
    const int b = blockIdx.x >> 6;
    const int n0 = (blockIdx.x & 63) * 64;
    const double* qb = QN + (size_t)b * 4096 * 512;
    int c0 = 0;                       // wave-0 per-row append cursor

    for (int mc = 0; mc < 64; ++mc) {
        const int m0 = mc * 64;
        double acc[16] = {};
        for (int kp = 0; kp < 8; ++kp) {
            __syncthreads();          // also orders prev chunk's Uc scan before reuse
            for (int q = 0; q < 16; ++q) {
                int id = q * 256 + t, r = id >> 6, c = id & 63;
                An[r][c] = qb[(size_t)(n0 + r) * 512 + kp * 64 + c];
                Bm[r][c] = qb[(size_t)(m0 + r) * 512 + kp * 64 + c];
            }
            __syncthreads();
            for (int kk = 0; kk < 64; ++kk) {
                double av[4], bv[4];
                for (int i = 0; i < 4; ++i) av[i] = An[tn + 16 * i][kk];
                for (int j = 0; j < 4; ++j) bv[j] = Bm[te + 16 * j][kk];
                for (int i = 0; i < 4; ++i)
                    for (int j = 0; j < 4; ++j) acc[i * 4 + j] += av[i] * bv[j];
            }
        }
        __syncthreads();
        for (int i = 0; i < 4; ++i)
            for (int j = 0; j < 4; ++j)
                Uc[tn + 16 * i][te + 16 * j] = acc[i * 4 + j];
        __syncthreads();
        if (t < 64) {                 // whole wave 0: no divergence
            size_t rowg = (size_t)b * 4096 + n0 + t;
            for (int j = 0; j < 64; ++j) {
                double cs = Uc[t][j];
                if (cs > 0.1 && c0 < CAP) {           // fp64 decision
                    idxs[rowg * CAP + c0] = (uint16_t)(m0 + j);
                    vals[rowg * CAP + c0] = (bf16)(float)cs;
                    ++c0;
                }
            }
        }
    }
    if (t < 64) counts[(size_t)b * 4096 + n0 + t] = (uint32_t)c0;
}

// ---------------------------------------------------------------------------
// K4: out[row,e] = LN( sum_m a_m v[m,e] ) in fp32, fp32 output.
// Defensive clamps (no-ops on healthy runs): c in [0,CAP], m in [0,4095].
// ---------------------------------------------------------------------------
__global__ __launch_bounds__(512) void pv_ln(const bf16* __restrict__ V,
                                             const uint32_t* __restrict__ counts,
                                             const uint16_t* __restrict__ idxs,
                                             const bf16* __restrict__ vals,
                                             const float* __restrict__ gamma,
                                             const float* __restrict__ beta,
                                             float* __restrict__ Out) {
    __shared__ float red[512];
    const int row = blockIdx.x;
    const int b = row >> 12;
    const int e = threadIdx.x;
    const bf16* vb = V + (size_t)b * 4096 * 512;
    int c = (int)counts[row];
    c = c < 0 ? 0 : (c > CAP ? CAP : c);
    const size_t base = (size_t)row * CAP;
    float acc = 0.f;
    for (int k = 0; k < c; ++k) {
        int m = idxs[base + k] & 4095;
        float a = (float)vals[base + k];
        acc += a * (float)vb[(size_t)m * 512 + e];
    }
    red[e] = acc; __syncthreads();
    for (int s = 256; s > 0; s >>= 1) {
        if (e < s) red[e] += red[e + s];
        __syncthreads();
    }
    float mean = red[0] * (1.0f / 512.0f);
    __syncthreads();
    float d = acc - mean;
    red[e] = d * d; __syncthreads();
    for (int s = 256; s > 0; s >>= 1) {
        if (e < s) red[e] += red[e + s];
        __syncthreads();
    }
    float var = red[0] * (1.0f / 512.0f);
    float rstd = 1.0f / sqrtf(var + 1e-5f);
    float y = (acc - mean) * rstd * gamma[e] + beta[e];
    Out[(size_t)row * 512 + e] = y;
}

// ---------------------------------------------------------------------------
extern "C" void kernel_launch(void* const* d_in, const int* in_sizes, int n_in,
                              void* d_out, int out_size, void* d_ws, size_t ws_size,
                              hipStream_t stream) {
    const float* x     = (const float*)d_in[0];   // [4,4096,512] fp32
    const float* wqk   = (const float*)d_in[1];   // [512,512]
    const float* wv    = (const float*)d_in[2];   // [512,512]
    const float* gamma = (const float*)d_in[3];   // [512]
    const float* beta  = (const float*)d_in[4];   // [512]
    float* out = (float*)d_out;                   // [4,4096,512] fp32

    char* ws = (char*)d_ws;
    double*   qn     = (double*)ws;                         // 64 MiB
    bf16*     v      = (bf16*)(ws + 67108864);              // 16 MiB
    uint32_t* counts = (uint32_t*)(ws + 83886080);          // 64 KiB
    uint16_t* idxs   = (uint16_t*)(ws + 83951616);          // 24 MiB (CAP=768)
    bf16*     vals   = (bf16*)(ws + 83951616 + (size_t)16384 * CAP * 2);
    const size_t need = 83951616 + (size_t)16384 * CAP * 4;  // 134,283,264 B
    if (ws_size < need) return;

    proj_f64<<<dim3(256, 8), 256, 0, stream>>>(x, wqk, qn);
    proj_v<<<dim3(256, 8), 256, 0, stream>>>(x, wv, v);
    norm_f64<<<64, 256, 0, stream>>>(qn);
    qk_f64<<<256, 256, 0, stream>>>(qn, counts, idxs, vals);
    pv_ln<<<16384, 512, 0, stream>>>(v, counts, idxs, vals, gamma, beta, out);
}

// Round 6
// 2339.622 us; speedup vs baseline: 2.0009x; 2.0009x over previous
//
#include <hip/hip_runtime.h>
#include <hip/hip_bf16.h>
#include <stdint.h>

// SimTransformer — fp32 I/O, fp64 mask chain (R5 passed: absmax 0.031).
// R6: replace brute-force fp64 QQ^T (3.25 ms, MfmaUtil 0) with bf16-MFMA
// prefilter + fp64 re-verify of |cos-0.1|<1.5e-3 band only (21-sigma band;
// ~0.2% of pairs). Mask decisions remain fp64-exact. ws = 151,060,480 B,
// exactly the R2-proven lower bound on ws_size.

typedef __bf16 bf16;
typedef __bf16 bf16x8 __attribute__((ext_vector_type(8)));
typedef float f4 __attribute__((ext_vector_type(4)));

#define CAP 768
#define BAND 0.0015f
#define BCAP 6144

// ---------------------------------------------------------------------------
// K1: Q[n,e] = sum_d X[n,d]*W[e,d] in fp64. 64x64 tile, 256 thr (unchanged).
// ---------------------------------------------------------------------------
__global__ __launch_bounds__(256) void proj_f64(const float* __restrict__ X,
                                                const float* __restrict__ W,
                                                double* __restrict__ Q) {
    __shared__ double As[64][66];
    __shared__ double Bs[64][66];
    const int t = threadIdx.x, tn = t >> 4, te = t & 15;
    const int n0 = blockIdx.x * 64, e0 = blockIdx.y * 64;
    double acc[4][4] = {};
    for (int p = 0; p < 8; ++p) {
        __syncthreads();
        for (int q = 0; q < 16; ++q) {
            int id = q * 256 + t, r = id >> 6, c = id & 63;
            As[r][c] = (double)X[(size_t)(n0 + r) * 512 + p * 64 + c];
            Bs[r][c] = (double)W[(size_t)(e0 + r) * 512 + p * 64 + c];
        }
        __syncthreads();
        for (int kk = 0; kk < 64; ++kk) {
            double av[4], bv[4];
            for (int i = 0; i < 4; ++i) av[i] = As[tn + 16 * i][kk];
            for (int j = 0; j < 4; ++j) bv[j] = Bs[te + 16 * j][kk];
            for (int i = 0; i < 4; ++i)
                for (int j = 0; j < 4; ++j) acc[i][j] += av[i] * bv[j];
        }
    }
    for (int i = 0; i < 4; ++i)
        for (int j = 0; j < 4; ++j)
            Q[(size_t)(n0 + tn + 16 * i) * 512 + e0 + te + 16 * j] = acc[i][j];
}

// ---------------------------------------------------------------------------
// K1b: V = X Wv^T, fp32 accum, bf16 out (unchanged, proven).
// ---------------------------------------------------------------------------
__global__ __launch_bounds__(256) void proj_v(const float* __restrict__ X,
                                              const float* __restrict__ W,
                                              bf16* __restrict__ C) {
    __shared__ float As[64][132];
    __shared__ float Bs[64][132];
    const int t = threadIdx.x, tn = t >> 4, te = t & 15;
    const int n0 = blockIdx.x * 64, e0 = blockIdx.y * 64;
    f4 acc[4][4] = {};
    for (int p = 0; p < 4; ++p) {
        __syncthreads();
        for (int q = 0; q < 8; ++q) {
            int id = q * 256 + t, r = id >> 5, c = (id & 31) * 4;
            *(f4*)&As[r][c] = *(const f4*)&X[(size_t)(n0 + r) * 512 + p * 128 + c];
            *(f4*)&Bs[r][c] = *(const f4*)&W[(size_t)(e0 + r) * 512 + p * 128 + c];
        }
        __syncthreads();
        for (int kk = 0; kk < 32; ++kk) {
            f4 av[4], bv[4];
            for (int i = 0; i < 4; ++i) av[i] = *(const f4*)&As[tn + 16 * i][kk * 4];
            for (int j = 0; j < 4; ++j) bv[j] = *(const f4*)&Bs[te + 16 * j][kk * 4];
            for (int i = 0; i < 4; ++i)
                for (int j = 0; j < 4; ++j) acc[i][j] += av[i] * bv[j];
        }
    }
    for (int i = 0; i < 4; ++i)
        for (int j = 0; j < 4; ++j) {
            f4 a = acc[i][j];
            C[(size_t)(n0 + tn + 16 * i) * 512 + e0 + te + 16 * j] =
                (bf16)((a.x + a.y) + (a.z + a.w));
        }
}

// ---------------------------------------------------------------------------
// K2: wave-per-row fp64 normalize; writes qn (fp64) and qnb (bf16).
// grid 4096 x 256 threads (4 rows/block).
// ---------------------------------------------------------------------------
__global__ __launch_bounds__(256) void norm_q(double* __restrict__ Q,
                                              bf16* __restrict__ QB) {
    const int wave = threadIdx.x >> 6, lane = threadIdx.x & 63;
    const int row = blockIdx.x * 4 + wave;
    double* q = Q + (size_t)row * 512;
    bf16* qb = QB + (size_t)row * 512;
    double x[8];
    double s = 0.0;
    for (int j = 0; j < 8; ++j) { x[j] = q[lane * 8 + j]; s += x[j] * x[j]; }
    for (int off = 1; off < 64; off <<= 1) s += __shfl_xor(s, off);
    double nm = fmax(sqrt(s), 1e-12);
    for (int j = 0; j < 8; ++j) {
        double qq = x[j] / nm;
        q[lane * 8 + j] = qq;
        qb[lane * 8 + j] = (bf16)(float)qq;
    }
}

// ---------------------------------------------------------------------------
// K3: bf16-MFMA cosine prefilter + fp64 borderline re-verify.
// grid 256 (4 b x 64 n-tiles), 512 thr (8 waves: rg=w&3 row-group, ch=w>>2).
// Qs (64x512 bf16) resident; QM staged in 128-row x 128-k panels.
// Accept cs>0.1+BAND; reject cs<0.1-BAND; else fp64 dot decides.
// ---------------------------------------------------------------------------
__global__ __launch_bounds__(512) void qk_mfma(const double* __restrict__ QN,
                                               const bf16* __restrict__ QNB,
                                               uint32_t* __restrict__ counts,
                                               uint16_t* __restrict__ idxs,
                                               bf16* __restrict__ vals) {
    __shared__ bf16 Qs[64][520];       // 66,560 B
    __shared__ bf16 QMs[128][136];     // 34,816 B
    __shared__ int cnt[64];
    __shared__ int bcnt;
    __shared__ uint32_t blist[BCAP];   // 24,576 B   (total ~126 KB)

    const int t = threadIdx.x;
    const int wave = t >> 6, lane = t & 63;
    const int ln16 = lane & 15, hi4 = lane >> 4;
    const int rg = wave & 3, ch = wave >> 2;
    const int b = blockIdx.x >> 6;
    const int n0 = (blockIdx.x & 63) * 64;
    const size_t nb = (size_t)b * 4096;
    const bf16* qnb = QNB + nb * 512;
    const double* qnf = QN + nb * 512;

    for (int i = 0; i < 8; ++i) {
        int id = i * 512 + t, r = id >> 6, g = id & 63;
        *(bf16x8*)&Qs[r][g * 8] = *(const bf16x8*)&qnb[(size_t)(n0 + r) * 512 + g * 8];
    }
    if (t < 64) cnt[t] = 0;
    if (t == 0) bcnt = 0;

    const int rl = rg * 16 + hi4 * 4;  // C/D row base (col=lane&15, row=hi4*4+i)

    for (int m0 = 0; m0 < 4096; m0 += 128) {
        f4 S[4] = {};
        for (int k0 = 0; k0 < 512; k0 += 128) {
            __syncthreads();           // QMs safe to overwrite (also covers init)
            for (int i = 0; i < 4; ++i) {
                int id = i * 512 + t, r = id >> 4, g = id & 15;
                *(bf16x8*)&QMs[r][g * 8] =
                    *(const bf16x8*)&qnb[(size_t)(m0 + r) * 512 + k0 + g * 8];
            }
            __syncthreads();
            for (int kk = 0; kk < 128; kk += 32) {
                bf16x8 a = *(const bf16x8*)&Qs[rg * 16 + ln16][k0 + kk + hi4 * 8];
                for (int tt = 0; tt < 4; ++tt) {
                    bf16x8 bb = *(const bf16x8*)&QMs[ch * 64 + tt * 16 + ln16][kk + hi4 * 8];
                    S[tt] = __builtin_amdgcn_mfma_f32_16x16x32_bf16(a, bb, S[tt], 0, 0, 0);
                }
            }
        }
        for (int tt = 0; tt < 4; ++tt) {
            int m = m0 + ch * 64 + tt * 16 + ln16;
            for (int i = 0; i < 4; ++i) {
                float cs = S[tt][i];
                int row = rl + i;
                if (cs > 0.1f + BAND) {
                    int pos = atomicAdd(&cnt[row], 1);
                    if (pos < CAP) {
                        size_t o = (nb + n0 + row) * CAP + pos;
                        idxs[o] = (uint16_t)m;
                        vals[o] = (bf16)cs;
                    }
                } else if (cs > 0.1f - BAND) {
                    int bp = atomicAdd(&bcnt, 1);
                    if (bp < BCAP) blist[bp] = ((uint32_t)row << 12) | (uint32_t)m;
                }
            }
        }
    }
    __syncthreads();
    int nbd = bcnt; if (nbd > BCAP) nbd = BCAP;
    for (int i = t; i < nbd; i += 512) {
        uint32_t pk = blist[i];
        int row = (int)(pk >> 12), m = (int)(pk & 4095);
        const double* qa = qnf + (size_t)(n0 + row) * 512;
        const double* qc = qnf + (size_t)m * 512;
        double s = 0.0;
        for (int k = 0; k < 512; ++k) s += qa[k] * qc[k];
        if (s > 0.1) {
            int pos = atomicAdd(&cnt[row], 1);
            if (pos < CAP) {
                size_t o = (nb + n0 + row) * CAP + pos;
                idxs[o] = (uint16_t)m;
                vals[o] = (bf16)(float)s;
            }
        }
    }
    __syncthreads();
    if (t < 64) {
        int c = cnt[t];
        counts[nb + n0 + t] = (uint32_t)(c > CAP ? CAP : c);
    }
}

// ---------------------------------------------------------------------------
// K4: out[row,e] = LN( sum_m a_m v[m,e] ), fp32 out (unchanged, proven).
// ---------------------------------------------------------------------------
__global__ __launch_bounds__(512) void pv_ln(const bf16* __restrict__ V,
                                             const uint32_t* __restrict__ counts,
                                             const uint16_t* __restrict__ idxs,
                                             const bf16* __restrict__ vals,
                                             const float* __restrict__ gamma,
                                             const float* __restrict__ beta,
                                             float* __restrict__ Out) {
    __shared__ float red[512];
    const int row = blockIdx.x;
    const int b = row >> 12;
    const int e = threadIdx.x;
    const bf16* vb = V + (size_t)b * 4096 * 512;
    int c = (int)counts[row];
    c = c < 0 ? 0 : (c > CAP ? CAP : c);
    const size_t base = (size_t)row * CAP;
    float acc = 0.f;
    for (int k = 0; k < c; ++k) {
        int m = idxs[base + k] & 4095;
        float a = (float)vals[base + k];
        acc += a * (float)vb[(size_t)m * 512 + e];
    }
    red[e] = acc; __syncthreads();
    for (int s = 256; s > 0; s >>= 1) {
        if (e < s) red[e] += red[e + s];
        __syncthreads();
    }
    float mean = red[0] * (1.0f / 512.0f);
    __syncthreads();
    float d = acc - mean;
    red[e] = d * d; __syncthreads();
    for (int s = 256; s > 0; s >>= 1) {
        if (e < s) red[e] += red[e + s];
        __syncthreads();
    }
    float var = red[0] * (1.0f / 512.0f);
    float rstd = 1.0f / sqrtf(var + 1e-5f);
    float y = (acc - mean) * rstd * gamma[e] + beta[e];
    Out[(size_t)row * 512 + e] = y;
}

// ---------------------------------------------------------------------------
extern "C" void kernel_launch(void* const* d_in, const int* in_sizes, int n_in,
                              void* d_out, int out_size, void* d_ws, size_t ws_size,
                              hipStream_t stream) {
    const float* x     = (const float*)d_in[0];   // [4,4096,512] fp32
    const float* wqk   = (const float*)d_in[1];   // [512,512]
    const float* wv    = (const float*)d_in[2];   // [512,512]
    const float* gamma = (const float*)d_in[3];   // [512]
    const float* beta  = (const float*)d_in[4];   // [512]
    float* out = (float*)d_out;                   // [4,4096,512] fp32

    char* ws = (char*)d_ws;
    double*   qn     = (double*)ws;                          // 64 MiB
    bf16*     qnb    = (bf16*)(ws + 67108864);               // 16 MiB
    bf16*     v      = (bf16*)(ws + 83886080);               // 16 MiB
    uint32_t* counts = (uint32_t*)(ws + 100663296);          // 64 KiB
    uint16_t* idxs   = (uint16_t*)(ws + 100728832);          // 24 MiB
    bf16*     vals   = (bf16*)(ws + 125894656);              // 24 MiB
    const size_t need = 151060480;  // == R2-proven ws_size lower bound
    if (ws_size < need) return;

    proj_f64<<<dim3(256, 8), 256, 0, stream>>>(x, wqk, qn);
    proj_v<<<dim3(256, 8), 256, 0, stream>>>(x, wv, v);
    norm_q<<<4096, 256, 0, stream>>>(qn, qnb);
    qk_mfma<<<256, 512, 0, stream>>>(qn, qnb, counts, idxs, vals);
    pv_ln<<<16384, 512, 0, stream>>>(v, counts, idxs, vals, gamma, beta, out);
}

// Round 7
// 1226.947 us; speedup vs baseline: 3.8154x; 1.9069x over previous
//
#include <hip/hip_runtime.h>
#include <hip/hip_bf16.h>
#include <stdint.h>

// SimTransformer — fp32 I/O, fp64 mask chain (R5/R6 passed, absmax 0.031).
// R7: pv_ln (1328us latency-bound gather) -> MFMA PV with dense weight-tile
// reconstruction from chunk-sorted sparse lists + fused LayerNorm.
// qk_mfma: borderline fp64 verify moved inline per m-chunk (wave-parallel
// dots) so lists stay sorted by 128-m chunk. proj_v now emits VT[b][e][m].

typedef __bf16 bf16;
typedef __bf16 bf16x8 __attribute__((ext_vector_type(8)));
typedef float f4 __attribute__((ext_vector_type(4)));

#define CAP 768
#define BAND 0.0015f
#define BCAPC 512   // borderline pairs per 128-m chunk (mean ~43, 70 sigma)

// ---------------------------------------------------------------------------
// K1: Q[n,e] = sum_d X[n,d]*W[e,d] in fp64. 64x64 tile, 256 thr (proven).
// ---------------------------------------------------------------------------
__global__ __launch_bounds__(256) void proj_f64(const float* __restrict__ X,
                                                const float* __restrict__ W,
                                                double* __restrict__ Q) {
    __shared__ double As[64][66];
    __shared__ double Bs[64][66];
    const int t = threadIdx.x, tn = t >> 4, te = t & 15;
    const int n0 = blockIdx.x * 64, e0 = blockIdx.y * 64;
    double acc[4][4] = {};
    for (int p = 0; p < 8; ++p) {
        __syncthreads();
        for (int q = 0; q < 16; ++q) {
            int id = q * 256 + t, r = id >> 6, c = id & 63;
            As[r][c] = (double)X[(size_t)(n0 + r) * 512 + p * 64 + c];
            Bs[r][c] = (double)W[(size_t)(e0 + r) * 512 + p * 64 + c];
        }
        __syncthreads();
        for (int kk = 0; kk < 64; ++kk) {
            double av[4], bv[4];
            for (int i = 0; i < 4; ++i) av[i] = As[tn + 16 * i][kk];
            for (int j = 0; j < 4; ++j) bv[j] = Bs[te + 16 * j][kk];
            for (int i = 0; i < 4; ++i)
                for (int j = 0; j < 4; ++j) acc[i][j] += av[i] * bv[j];
        }
    }
    for (int i = 0; i < 4; ++i)
        for (int j = 0; j < 4; ++j)
            Q[(size_t)(n0 + tn + 16 * i) * 512 + e0 + te + 16 * j] = acc[i][j];
}

// ---------------------------------------------------------------------------
// K1b: VT[b][e][m] = (X Wv^T)[m,e], fp32 accum, bf16 out, LDS-transposed.
// ---------------------------------------------------------------------------
__global__ __launch_bounds__(256) void proj_v(const float* __restrict__ X,
                                              const float* __restrict__ W,
                                              bf16* __restrict__ VT) {
    __shared__ float As[64][132];
    __shared__ float Bs[64][132];
    __shared__ bf16 Tt[64][72];   // [e-local][m-local]
    const int t = threadIdx.x, tn = t >> 4, te = t & 15;
    const int n0 = blockIdx.x * 64, e0 = blockIdx.y * 64;
    f4 acc[4][4] = {};
    for (int p = 0; p < 4; ++p) {
        __syncthreads();
        for (int q = 0; q < 8; ++q) {
            int id = q * 256 + t, r = id >> 5, c = (id & 31) * 4;
            *(f4*)&As[r][c] = *(const f4*)&X[(size_t)(n0 + r) * 512 + p * 128 + c];
            *(f4*)&Bs[r][c] = *(const f4*)&W[(size_t)(e0 + r) * 512 + p * 128 + c];
        }
        __syncthreads();
        for (int kk = 0; kk < 32; ++kk) {
            f4 av[4], bv[4];
            for (int i = 0; i < 4; ++i) av[i] = *(const f4*)&As[tn + 16 * i][kk * 4];
            for (int j = 0; j < 4; ++j) bv[j] = *(const f4*)&Bs[te + 16 * j][kk * 4];
            for (int i = 0; i < 4; ++i)
                for (int j = 0; j < 4; ++j) acc[i][j] += av[i] * bv[j];
        }
    }
    for (int i = 0; i < 4; ++i)
        for (int j = 0; j < 4; ++j) {
            f4 a = acc[i][j];
            Tt[te + 16 * j][tn + 16 * i] = (bf16)((a.x + a.y) + (a.z + a.w));
        }
    __syncthreads();
    const int b = n0 >> 12, ml = n0 & 4095;
    for (int i2 = 0; i2 < 2; ++i2) {
        int id = i2 * 256 + t, er = id >> 3, g = (id & 7) * 8;
        *(bf16x8*)&VT[((size_t)b * 512 + e0 + er) * 4096 + ml + g] =
            *(bf16x8*)&Tt[er][g];
    }
}

// ---------------------------------------------------------------------------
// K2: wave-per-row fp64 normalize; writes qn (fp64) and qnb (bf16). (proven)
// ---------------------------------------------------------------------------
__global__ __launch_bounds__(256) void norm_q(double* __restrict__ Q,
                                              bf16* __restrict__ QB) {
    const int wave = threadIdx.x >> 6, lane = threadIdx.x & 63;
    const int row = blockIdx.x * 4 + wave;
    double* q = Q + (size_t)row * 512;
    bf16* qb = QB + (size_t)row * 512;
    double x[8];
    double s = 0.0;
    for (int j = 0; j < 8; ++j) { x[j] = q[lane * 8 + j]; s += x[j] * x[j]; }
    for (int off = 1; off < 64; off <<= 1) s += __shfl_xor(s, off);
    double nm = fmax(sqrt(s), 1e-12);
    for (int j = 0; j < 8; ++j) {
        double qq = x[j] / nm;
        q[lane * 8 + j] = qq;
        qb[lane * 8 + j] = (bf16)(float)qq;
    }
}

// ---------------------------------------------------------------------------
// K3: bf16-MFMA cosine prefilter + INLINE per-chunk fp64 borderline verify
// (wave-parallel dots) -> lists chunk-sorted in m. grid 256, 512 thr.
// ---------------------------------------------------------------------------
__global__ __launch_bounds__(512) void qk_mfma(const double* __restrict__ QN,
                                               const bf16* __restrict__ QNB,
                                               uint32_t* __restrict__ counts,
                                               uint16_t* __restrict__ idxs,
                                               bf16* __restrict__ vals) {
    __shared__ bf16 Qs[64][520];       // 66,560 B
    __shared__ bf16 QMs[128][136];     // 34,816 B
    __shared__ int cnt[64];
    __shared__ int bcnt;
    __shared__ uint32_t blist[BCAPC];  // 2,048 B   (total ~104 KB)

    const int t = threadIdx.x;
    const int wave = t >> 6, lane = t & 63;
    const int ln16 = lane & 15, hi4 = lane >> 4;
    const int rg = wave & 3, ch = wave >> 2;
    const int b = blockIdx.x >> 6;
    const int n0 = (blockIdx.x & 63) * 64;
    const size_t nb = (size_t)b * 4096;
    const bf16* qnb = QNB + nb * 512;
    const double* qnf = QN + nb * 512;

    for (int i = 0; i < 8; ++i) {
        int id = i * 512 + t, r = id >> 6, g = id & 63;
        *(bf16x8*)&Qs[r][g * 8] = *(const bf16x8*)&qnb[(size_t)(n0 + r) * 512 + g * 8];
    }
    if (t < 64) cnt[t] = 0;
    if (t == 0) bcnt = 0;

    const int rl = rg * 16 + hi4 * 4;

    for (int m0 = 0; m0 < 4096; m0 += 128) {
        f4 S[4] = {};
        for (int k0 = 0; k0 < 512; k0 += 128) {
            __syncthreads();           // QMs safe; also orders bcnt reset/init
            for (int i = 0; i < 4; ++i) {
                int id = i * 512 + t, r = id >> 4, g = id & 15;
                *(bf16x8*)&QMs[r][g * 8] =
                    *(const bf16x8*)&qnb[(size_t)(m0 + r) * 512 + k0 + g * 8];
            }
            __syncthreads();
            for (int kk = 0; kk < 128; kk += 32) {
                bf16x8 a = *(const bf16x8*)&Qs[rg * 16 + ln16][k0 + kk + hi4 * 8];
                for (int tt = 0; tt < 4; ++tt) {
                    bf16x8 bb = *(const bf16x8*)&QMs[ch * 64 + tt * 16 + ln16][kk + hi4 * 8];
                    S[tt] = __builtin_amdgcn_mfma_f32_16x16x32_bf16(a, bb, S[tt], 0, 0, 0);
                }
            }
        }
        // threshold: accept / borderline-to-blist
        for (int tt = 0; tt < 4; ++tt) {
            int m = m0 + ch * 64 + tt * 16 + ln16;
            for (int i = 0; i < 4; ++i) {
                float cs = S[tt][i];
                int row = rl + i;
                if (cs > 0.1f + BAND) {
                    int pos = atomicAdd(&cnt[row], 1);
                    if (pos < CAP) {
                        size_t o = (nb + n0 + row) * CAP + pos;
                        idxs[o] = (uint16_t)m;
                        vals[o] = (bf16)cs;
                    }
                } else if (cs > 0.1f - BAND) {
                    int bp = atomicAdd(&bcnt, 1);
                    if (bp < BCAPC) blist[bp] = ((uint32_t)row << 12) | (uint32_t)m;
                }
            }
        }
        __syncthreads();               // blist complete
        int nbd = bcnt; if (nbd > BCAPC) nbd = BCAPC;
        for (int p = wave; p < nbd; p += 8) {   // wave-parallel fp64 dots
            uint32_t pk = blist[p];
            int row = (int)(pk >> 12), m = (int)(pk & 4095);
            const double* qa = qnf + (size_t)(n0 + row) * 512;
            const double* qc = qnf + (size_t)m * 512;
            double s = 0.0;
            for (int j = 0; j < 8; ++j) s += qa[lane * 8 + j] * qc[lane * 8 + j];
            for (int off = 1; off < 64; off <<= 1) s += __shfl_xor(s, off);
            if (lane == 0 && s > 0.1) {
                int pos = atomicAdd(&cnt[row], 1);
                if (pos < CAP) {
                    size_t o = (nb + n0 + row) * CAP + pos;
                    idxs[o] = (uint16_t)m;
                    vals[o] = (bf16)(float)s;
                }
            }
        }
        __syncthreads();               // verify appends done
        if (t == 0) bcnt = 0;          // next chunk (ordered by staging barrier)
    }
    __syncthreads();
    if (t < 64) {
        int c = cnt[t];
        counts[nb + n0 + t] = (uint32_t)(c > CAP ? CAP : c);
    }
}

// ---------------------------------------------------------------------------
// K4: MFMA PV + fused LayerNorm. grid 512 (4 b x 128 32-row tiles), 512 thr.
// 8 waves: rg=w&1 (16-row group), et=w>>1 (e-tile pair within each 128-chunk).
// Per 128-m chunk: row-owner zero+scatter of W tile from sorted lists, then
// for cc 0..3: stage Vts (128e x 128m), O += W * V^T.
// ---------------------------------------------------------------------------
__global__ __launch_bounds__(512) void pv_mfma(const bf16* __restrict__ VT,
                                               const uint32_t* __restrict__ counts,
                                               const uint16_t* __restrict__ idxs,
                                               const bf16* __restrict__ vals,
                                               const float* __restrict__ gamma,
                                               const float* __restrict__ beta,
                                               float* __restrict__ Out) {
    __shared__ bf16 Wsm[32][136];      //  8,704 B
    __shared__ bf16 Vts[128][136];     // 34,816 B
    __shared__ int cur[32];
    __shared__ float red[4][32][2];    //  1,024 B  (total ~45 KB)

    const int t = threadIdx.x;
    const int wave = t >> 6, lane = t & 63;
    const int ln16 = lane & 15, hi4 = lane >> 4;
    const int rg = wave & 1, et = wave >> 1;
    const int b = blockIdx.x >> 7;
    const int n0 = (blockIdx.x & 127) * 32;
    const size_t nb = (size_t)b * 4096;
    const bf16* vtb = VT + (size_t)b * 512 * 4096;

    int myc = 0;
    if (t < 32) {
        int c = (int)counts[nb + n0 + t];
        myc = c < 0 ? 0 : (c > CAP ? CAP : c);
        cur[t] = 0;
    }

    f4 O[8] = {};   // [cc*2+s]: rows rg*16+hi4*4+i, col cc*128+et*32+s*16+ln16

    for (int m0 = 0; m0 < 4096; m0 += 128) {
        __syncthreads();               // prev chunk's MFMA reads of Wsm done
        if (t < 32) {                  // row-owner: zero row + scatter entries
            uint32_t* wz = (uint32_t*)&Wsm[t][0];
            for (int j = 0; j < 68; ++j) wz[j] = 0;
            const size_t base = (nb + n0 + t) * CAP;
            int cu = cur[t];
            while (cu < myc) {
                int mi = (int)(idxs[base + cu] & 4095);
                if (mi >= m0 + 128) break;
                int lo = mi - m0;
                if (lo >= 0) Wsm[t][lo] = vals[base + cu];
                ++cu;
            }
            cur[t] = cu;
        }
        __syncthreads();               // W tile ready
        for (int cc = 0; cc < 4; ++cc) {
            for (int i = 0; i < 4; ++i) {
                int id = i * 512 + t, r = id >> 4, g = (id & 15) * 8;
                *(bf16x8*)&Vts[r][g] =
                    *(const bf16x8*)&vtb[(size_t)(cc * 128 + r) * 4096 + m0 + g];
            }
            __syncthreads();           // Vts ready
            for (int kk = 0; kk < 4; ++kk) {
                bf16x8 aw = *(const bf16x8*)&Wsm[rg * 16 + ln16][kk * 32 + hi4 * 8];
                for (int s2 = 0; s2 < 2; ++s2) {
                    bf16x8 bv = *(const bf16x8*)&Vts[et * 32 + s2 * 16 + ln16][kk * 32 + hi4 * 8];
                    O[cc * 2 + s2] = __builtin_amdgcn_mfma_f32_16x16x32_bf16(
                        aw, bv, O[cc * 2 + s2], 0, 0, 0);
                }
            }
            __syncthreads();           // Vts safe to overwrite
        }
    }

    // ---- fused LayerNorm over 512 cols ----
    const int rloc = rg * 16 + hi4 * 4;
    float ps[4] = {0, 0, 0, 0}, pq[4] = {0, 0, 0, 0};
    for (int idx = 0; idx < 8; ++idx)
        for (int i = 0; i < 4; ++i) {
            float v = O[idx][i]; ps[i] += v; pq[i] += v * v;
        }
    for (int off = 1; off < 16; off <<= 1)
        for (int i = 0; i < 4; ++i) {
            ps[i] += __shfl_xor(ps[i], off);
            pq[i] += __shfl_xor(pq[i], off);
        }
    if (ln16 == 0)
        for (int i = 0; i < 4; ++i) {
            red[et][rloc + i][0] = ps[i];
            red[et][rloc + i][1] = pq[i];
        }
    __syncthreads();
    float mu[4], rs[4];
    for (int i = 0; i < 4; ++i) {
        float s = red[0][rloc + i][0] + red[1][rloc + i][0] +
                  red[2][rloc + i][0] + red[3][rloc + i][0];
        float q2 = red[0][rloc + i][1] + red[1][rloc + i][1] +
                   red[2][rloc + i][1] + red[3][rloc + i][1];
        mu[i] = s * (1.0f / 512.0f);
        float var = q2 * (1.0f / 512.0f) - mu[i] * mu[i];
        rs[i] = rsqrtf(var + 1e-5f);
    }
    for (int cc = 0; cc < 4; ++cc)
        for (int s2 = 0; s2 < 2; ++s2) {
            int col = cc * 128 + et * 32 + s2 * 16 + ln16;
            float g = gamma[col], be = beta[col];
            for (int i = 0; i < 4; ++i) {
                float y = (O[cc * 2 + s2][i] - mu[i]) * rs[i] * g + be;
                Out[(nb + n0 + rloc + i) * 512 + col] = y;
            }
        }
}

// ---------------------------------------------------------------------------
extern "C" void kernel_launch(void* const* d_in, const int* in_sizes, int n_in,
                              void* d_out, int out_size, void* d_ws, size_t ws_size,
                              hipStream_t stream) {
    const float* x     = (const float*)d_in[0];
    const float* wqk   = (const float*)d_in[1];
    const float* wv    = (const float*)d_in[2];
    const float* gamma = (const float*)d_in[3];
    const float* beta  = (const float*)d_in[4];
    float* out = (float*)d_out;

    char* ws = (char*)d_ws;
    double*   qn     = (double*)ws;                          // 64 MiB
    bf16*     qnb    = (bf16*)(ws + 67108864);               // 16 MiB
    bf16*     vt     = (bf16*)(ws + 83886080);               // 16 MiB [4][512][4096]
    uint32_t* counts = (uint32_t*)(ws + 100663296);          // 64 KiB
    uint16_t* idxs   = (uint16_t*)(ws + 100728832);          // 24 MiB
    bf16*     vals   = (bf16*)(ws + 125894656);              // 24 MiB
    const size_t need = 151060480;  // == R2-proven ws_size lower bound
    if (ws_size < need) return;

    proj_f64<<<dim3(256, 8), 256, 0, stream>>>(x, wqk, qn);
    proj_v<<<dim3(256, 8), 256, 0, stream>>>(x, wv, vt);
    norm_q<<<4096, 256, 0, stream>>>(qn, qnb);
    qk_mfma<<<256, 512, 0, stream>>>(qn, qnb, counts, idxs, vals);
    pv_mfma<<<512, 512, 0, stream>>>(vt, counts, idxs, vals, gamma, beta, out);
}